// Round 18
// baseline (270.347 us; speedup 1.0000x reference)
//
#include <hip/hip_runtime.h>

#define TT 20
#define HH 64
#define RSZ 16384       // bin range width (both deg u16 bins and S fp32 bins)
#define NSLD 32         // edge slices
#define CAP 18432       // records per (range, slice) partition chunk
#define SPILLCAP (1 << 18)

typedef __attribute__((ext_vector_type(8))) short short8;   // 8 bf16 (MFMA A/B frag)
typedef __attribute__((ext_vector_type(4))) float f32x4;    // MFMA C/D frag

__device__ __forceinline__ unsigned fbits(float f) { union { float f; unsigned u; } v; v.f = f; return v.u; }
__device__ __forceinline__ float bcast(unsigned u) { union { float f; unsigned u; } v; v.u = u; return v.f; }

// Fused: blocks [0, RD*NSLD) = deg histogram + edge partition (VMEM/L3 pipes);
// blocks >= RD*NSLD = pure MFMA RNN (VALU/LDS/MFMA pipes).
// launch_bounds (256,3): don't squeeze the allocator below the RNN's ~76 live regs
// (R16: forced 64 VGPR -> 23 MB scratch). Cursor reservations are wave-aggregated
// (R17: per-thread same-address LDS atomics serialized the deg path).
__global__ __launch_bounds__(256, 3) void k_fused(
    const float* __restrict__ x,
    const float* __restrict__ W_ih, const float* __restrict__ b_ih,
    const float* __restrict__ W_hh, const float* __restrict__ b_hh,
    const float* __restrict__ W_gcn, const float* __restrict__ W_fc,
    const int* __restrict__ ei, unsigned* __restrict__ degrep,
    unsigned* __restrict__ Part, int* __restrict__ cnt,
    int* __restrict__ spill, int* __restrict__ spillCur,
    float* __restrict__ z, int N, int E, int RD, int N2)
{
    __shared__ __align__(16) unsigned smem[8192];   // 32 KB
    __shared__ int scur;

    const int t = threadIdx.x;
    const int RDN = RD * NSLD;

    if (blockIdx.x < RDN) {
        // ---- deg histogram (packed u16 LDS bins) + edge partition ----
        unsigned* bin = smem;
        const int r = blockIdx.x % RD;
        const int s = blockIdx.x / RD;
        const int base = r * RSZ;
        const int l = t & 63;
        unsigned* part = Part + (size_t)((r * NSLD) + s) * CAP;
        for (int i = t; i < RSZ / 2; i += 256) bin[i] = 0;
        if (t == 0) scur = 0;
        __syncthreads();
        const long long P = (long long)(E >> 1);
        const long long pb = s * P / NSLD;
        const long long pe = (s + 1) * P / NSLD;
        const int4* ei4 = (const int4*)ei;
        for (long long g = pb + t; g < pe; g += 256) {
            int4 q = ei4[g];
#pragma unroll
            for (int h = 0; h < 2; ++h) {
                int src = h ? q.z : q.x;
                int dst = h ? q.w : q.y;
                unsigned u = (unsigned)(dst - base);
                const bool pred = (u < RSZ);
                if (pred) atomicAdd(&bin[u >> 1], 1u << ((u & 1) << 4));
                // wave-aggregated reservation: 1 LDS cursor atomic per wave
                unsigned long long mask = __ballot(pred);
                if (mask) {
                    int leader = __ffsll((long long)mask) - 1;
                    int basePos = 0;
                    if (l == leader) basePos = atomicAdd(&scur, (int)__popcll(mask));
                    basePos = __shfl(basePos, leader, 64);
                    if (pred) {
                        int pos = basePos + (int)__popcll(mask & ((1ull << l) - 1ull));
                        if (pos < CAP) part[pos] = (u << 18) | (unsigned)src;
                        else {
                            int sp = atomicAdd(spillCur, 1);
                            if (sp < SPILLCAP) { spill[2 * sp] = src; spill[2 * sp + 1] = dst; }
                        }
                    }
                }
            }
        }
        if ((E & 1) && s == NSLD - 1 && t == 0) {
            int src = ei[2 * (E - 1)], dst = ei[2 * (E - 1) + 1];
            unsigned u = (unsigned)(dst - base);
            if (u < RSZ) {
                atomicAdd(&bin[u >> 1], 1u << ((u & 1) << 4));
                int pos = atomicAdd(&scur, 1);
                if (pos < CAP) part[pos] = (u << 18) | (unsigned)src;
                else {
                    int sp = atomicAdd(spillCur, 1);
                    if (sp < SPILLCAP) { spill[2 * sp] = src; spill[2 * sp + 1] = dst; }
                }
            }
        }
        __syncthreads();
        const int lim = min(RSZ, N - base);
        const int words = (lim + 1) >> 1;
        unsigned* dstp = degrep + (size_t)s * N2 + (base >> 1);
        for (int i = t; i < words; i += 256) dstp[i] = bin[i];
        if (t == 0) cnt[r * NSLD + s] = scur;
        return;
    }

    // ---- MFMA RNN: 4 independent waves, 16 nodes each, wave-private LDS ----
    const int w    = t >> 6;
    const int l    = t & 63;
    const int nl   = l & 15;
    const int quad = l >> 4;
    const int n0   = (blockIdx.x - RDN) * 64 + w * 16;

    unsigned short* hh = (unsigned short*)&smem[w * 512];          // 1024 u16
    unsigned short* hl = (unsigned short*)&smem[2048 + w * 512];   // 1024 u16
    float*          sx = (float*)&smem[4096 + w * 320];            // 320 f32

    for (int i = l; i < 16 * TT; i += 64) {
        int nn = i / TT, tt = i - nn * TT;
        int n = n0 + nn; if (n >= N) n = N - 1;
        sx[tt * 16 + nn] = x[(size_t)n * TT + tt];
    }
    {
        uint4 zz = {0, 0, 0, 0};
        uint4* ph = (uint4*)hh;
        uint4* pl = (uint4*)hl;
#pragma unroll
        for (int i = 0; i < 2; ++i) { ph[l + 64 * i] = zz; pl[l + 64 * i] = zz; }
    }

    short8 Bh[4][2], Bl[4][2];
#pragma unroll
    for (int tt2 = 0; tt2 < 4; ++tt2)
#pragma unroll
        for (int kc = 0; kc < 2; ++kc) {
            const float* wr = W_hh + (size_t)(16 * tt2 + nl) * HH + kc * 32 + quad * 8;
            float4 w0 = *(const float4*)(wr);
            float4 w1 = *(const float4*)(wr + 4);
            float wvv[8] = {w0.x, w0.y, w0.z, w0.w, w1.x, w1.y, w1.z, w1.w};
            short8 sh, sl;
#pragma unroll
            for (int j = 0; j < 8; ++j) {
                unsigned u  = fbits(wvv[j]);
                unsigned hb = u & 0xffff0000u;
                float lo = wvv[j] - bcast(hb);
                sh[j] = (short)(hb >> 16);
                sl[j] = (short)(fbits(lo) >> 16);
            }
            Bh[tt2][kc] = sh; Bl[tt2][kc] = sl;
        }

    float vl = 0.0f;
#pragma unroll 8
    for (int j = 0; j < HH; ++j) vl = fmaf(W_fc[j], W_gcn[j * HH + l], vl);

    float wih4[4], bs4[4], vv[4];
#pragma unroll
    for (int tt2 = 0; tt2 < 4; ++tt2) {
        int n = nl + 16 * tt2;
        wih4[tt2] = W_ih[n];
        bs4[tt2]  = b_ih[n] + b_hh[n];
        vv[tt2]   = __shfl(vl, n, 64);
    }

    const int ra = (l ^ ((l >> 4) & 1)) * 8;

    f32x4 C[4];

    for (int step = 0; step < TT; ++step) {
        const float4 xr = *(const float4*)&sx[step * 16 + quad * 4];
#pragma unroll
        for (int tt2 = 0; tt2 < 4; ++tt2) {
            C[tt2][0] = fmaf(xr.x, wih4[tt2], bs4[tt2]);
            C[tt2][1] = fmaf(xr.y, wih4[tt2], bs4[tt2]);
            C[tt2][2] = fmaf(xr.z, wih4[tt2], bs4[tt2]);
            C[tt2][3] = fmaf(xr.w, wih4[tt2], bs4[tt2]);
        }

#pragma unroll
        for (int kc = 0; kc < 2; ++kc) {
            short8 Ah = *(const short8*)&hh[kc * 512 + ra];
            short8 Al = *(const short8*)&hl[kc * 512 + ra];
#pragma unroll
            for (int tt2 = 0; tt2 < 4; ++tt2) {
                C[tt2] = __builtin_amdgcn_mfma_f32_16x16x32_bf16(Ah, Bh[tt2][kc], C[tt2], 0, 0, 0);
                C[tt2] = __builtin_amdgcn_mfma_f32_16x16x32_bf16(Ah, Bl[tt2][kc], C[tt2], 0, 0, 0);
                C[tt2] = __builtin_amdgcn_mfma_f32_16x16x32_bf16(Al, Bh[tt2][kc], C[tt2], 0, 0, 0);
            }
        }

#pragma unroll
        for (int tt2 = 0; tt2 < 4; ++tt2) {
            const int kc_d = tt2 >> 1;
            const int qa   = (nl >> 3) + 2 * (tt2 & 1);
            const int jj   = nl & 7;
#pragma unroll
            for (int r = 0; r < 4; ++r) {
                float eg = __builtin_amdgcn_exp2f(C[tt2][r] * 2.885390081777927f);
                float hv = fmaf(-2.0f, __builtin_amdgcn_rcpf(eg + 1.0f), 1.0f);
                C[tt2][r] = hv;
                unsigned um = fbits(hv);
                unsigned hb = um & 0xffff0000u;
                float lo = hv - bcast(hb);
                const int m   = quad * 4 + r;
                const int la  = m + 16 * qa;
                const int idx = kc_d * 512 + (la ^ ((la >> 4) & 1)) * 8 + jj;
                hh[idx] = (unsigned short)(um >> 16);
                hl[idx] = (unsigned short)(fbits(lo) >> 16);
            }
        }
    }

#pragma unroll
    for (int r = 0; r < 4; ++r) {
        float p = 0.0f;
#pragma unroll
        for (int tt2 = 0; tt2 < 4; ++tt2) p = fmaf(C[tt2][r], vv[tt2], p);
        p += __shfl_xor(p, 1, 64);
        p += __shfl_xor(p, 2, 64);
        p += __shfl_xor(p, 4, 64);
        p += __shfl_xor(p, 8, 64);
        if (nl == 0) {
            const int n = n0 + quad * 4 + r;
            if (n < N) z[n] = p;
        }
    }
}

// reduce packed-u16 deg replicas; dinv = rsqrt(deg+1); w = dinv*z
__global__ __launch_bounds__(256) void k_w(const unsigned* __restrict__ degrep,
                                           const float* __restrict__ z,
                                           float* __restrict__ dinv,
                                           float* __restrict__ w, int N, int N2) {
    int n = blockIdx.x * blockDim.x + threadIdx.x;
    if (n >= N) return;
    const int wd = n >> 1, sh = (n & 1) << 4;
    unsigned d = 0;
#pragma unroll 8
    for (int s = 0; s < NSLD; ++s) d += (degrep[(size_t)s * N2 + wd] >> sh) & 0xffffu;
    float di = __frsqrt_rn((float)d + 1.0f);
    dinv[n] = di;
    w[n] = di * z[n];
}

// S aggregation from partitioned records: block (r,s) reads only chunk (r,s).
__global__ __launch_bounds__(1024) void k_sbin(const unsigned* __restrict__ Part,
                                               const int* __restrict__ cnt,
                                               const float* __restrict__ w,
                                               float* __restrict__ Srep,
                                               int N, int RD) {
    __shared__ float bin[RSZ];                    // 64 KB
    const int r = blockIdx.x % RD;
    const int s = blockIdx.x / RD;
    const int base = r * RSZ;
    for (int i = threadIdx.x; i < RSZ; i += 1024) bin[i] = 0.0f;
    __syncthreads();
    const int n = min(cnt[r * NSLD + s], CAP);
    const unsigned* part = Part + (size_t)((r * NSLD) + s) * CAP;
    for (int i = threadIdx.x; i < n; i += 1024) {
        unsigned rec = part[i];
        atomicAdd(&bin[rec >> 18], w[rec & 0x3ffffu]);
    }
    __syncthreads();
    const int lim = min(RSZ, N - base);
    float* dst = Srep + (size_t)s * N + base;
    for (int i = threadIdx.x; i < lim; i += 1024) dst[i] = bin[i];
}

// process rare partition-overflow records (device-scope atomics; ~0 in practice)
__global__ __launch_bounds__(256) void k_spill(const int* __restrict__ spill,
                                               const int* __restrict__ spillCur,
                                               const float* __restrict__ w,
                                               float* __restrict__ Srep) {
    int m = min(*spillCur, SPILLCAP);
    for (int i = threadIdx.x; i < m; i += 256)
        atomicAdd(&Srep[spill[2 * i + 1]], w[spill[2 * i]]);
}

// out = dinv*(sum S_rep) + dinv*w + c,  c = w_fc.b_gcn + b_fc
__global__ __launch_bounds__(256) void k_final(const float* __restrict__ dinv,
                                               const float* __restrict__ Srep,
                                               const float* __restrict__ w,
                                               const float* __restrict__ b_gcn,
                                               const float* __restrict__ W_fc,
                                               const float* __restrict__ b_fc,
                                               float* __restrict__ out, int N)
{
    float c = b_fc[0];
#pragma unroll 8
    for (int j = 0; j < HH; ++j) c = fmaf(W_fc[j], b_gcn[j], c);
    int n = blockIdx.x * blockDim.x + threadIdx.x;
    if (n >= N) return;
    float S = 0.0f;
#pragma unroll 8
    for (int s = 0; s < NSLD; ++s) S += Srep[(size_t)s * N + n];
    float d = dinv[n];
    out[n] = fmaf(d, S, fmaf(d, w[n], c));
}

extern "C" void kernel_launch(void* const* d_in, const int* in_sizes, int n_in,
                              void* d_out, int out_size, void* d_ws, size_t ws_size,
                              hipStream_t stream)
{
    const float* x     = (const float*)d_in[0];
    const int*   ei    = (const int*)d_in[1];
    const float* W_ih  = (const float*)d_in[2];
    const float* b_ih  = (const float*)d_in[3];
    const float* W_hh  = (const float*)d_in[4];
    const float* b_hh  = (const float*)d_in[5];
    const float* W_gcn = (const float*)d_in[6];
    const float* b_gcn = (const float*)d_in[7];
    const float* W_fc  = (const float*)d_in[8];
    const float* b_fc  = (const float*)d_in[9];
    float* out = (float*)d_out;

    const int N  = in_sizes[0] / TT;
    const int E  = in_sizes[1] / 2;
    const int N2 = (N + 1) / 2;
    const int RD = (N + RSZ - 1) / RSZ;        // ranges (shared by deg and S)

    char* ws = (char*)d_ws;
    size_t off = 0;
    auto alloc = [&](size_t bytes) { void* p = ws + off; off += (bytes + 255) & ~(size_t)255; return p; };
    unsigned* degrep  = (unsigned*)alloc((size_t)NSLD * N2 * 4);      // packed u16 pairs
    float*    Srep    = (float*)   alloc((size_t)NSLD * N * 4);
    unsigned* Part    = (unsigned*)alloc((size_t)RD * NSLD * CAP * 4);
    int*      cnt     = (int*)     alloc((size_t)RD * NSLD * 4);
    int*      spill   = (int*)     alloc((size_t)SPILLCAP * 8);
    int*      spillCur= (int*)     alloc(4);
    float*    z       = (float*)   alloc((size_t)N * 4);
    float*    dinv    = (float*)   alloc((size_t)N * 4);
    float*    w       = (float*)   alloc((size_t)N * 4);

    hipMemsetAsync(spillCur, 0, 4, stream);

    const int rnnBlocks = (N + 63) / 64;
    k_fused <<<RD * NSLD + rnnBlocks, 256, 0, stream>>>(x, W_ih, b_ih, W_hh, b_hh,
                                                        W_gcn, W_fc, ei, degrep,
                                                        Part, cnt, spill, spillCur,
                                                        z, N, E, RD, N2);
    k_w     <<<(N + 255) / 256, 256, 0, stream>>>(degrep, z, dinv, w, N, N2);
    k_sbin  <<<RD * NSLD, 1024, 0, stream>>>(Part, cnt, w, Srep, N, RD);
    k_spill <<<1, 256, 0, stream>>>(spill, spillCur, w, Srep);
    k_final <<<(N + 255) / 256, 256, 0, stream>>>(dinv, Srep, w, b_gcn, W_fc, b_fc, out, N);
}

// Round 19
// 239.813 us; speedup vs baseline: 1.1273x; 1.1273x over previous
//
#include <hip/hip_runtime.h>

#define TT 20
#define HH 64
#define RSZ 16384      // fp32 S-bin range (64 KB LDS)
#define DRSZ 16384     // u16 deg-bin range (32 KB LDS, shared with RNN path)
#define NSL 32         // edge slices for S pass: 7*32=224 blocks <= 256 CUs, one round
#define NSLD 32        // edge slices for fused deg pass

typedef __attribute__((ext_vector_type(8))) short short8;   // 8 bf16 (MFMA A/B frag)
typedef __attribute__((ext_vector_type(4))) float f32x4;    // MFMA C/D frag

__device__ __forceinline__ unsigned fbits(float f) { union { float f; unsigned u; } v; v.f = f; return v.u; }
__device__ __forceinline__ float bcast(unsigned u) { union { float f; unsigned u; } v; v.u = u; return v.f; }

// Fused: blocks [0, RD*NSLD) = deg histogram via LDS u16 bins (VMEM/L3 pipes);
// blocks >= RD*NSLD = pure MFMA RNN (VALU/LDS/MFMA pipes). One 32 KB smem pool.
__global__ __launch_bounds__(256, 4) void k_fused(
    const float* __restrict__ x,
    const float* __restrict__ W_ih, const float* __restrict__ b_ih,
    const float* __restrict__ W_hh, const float* __restrict__ b_hh,
    const float* __restrict__ W_gcn, const float* __restrict__ W_fc,
    const int* __restrict__ ei, unsigned* __restrict__ degrep,
    float* __restrict__ z, int N, int E, int RD, int N2)
{
    __shared__ __align__(16) unsigned smem[8192];   // 32 KB

    const int t = threadIdx.x;
    const int RDN = RD * NSLD;

    if (blockIdx.x < RDN) {
        // ---- deg histogram: packed-u16 LDS bins, int4 = 2 edges per load ----
        unsigned* bin = smem;                       // 8192 words = 16384 u16 bins
        const int r = blockIdx.x % RD;
        const int s = blockIdx.x / RD;
        const int base = r * DRSZ;
        for (int i = t; i < DRSZ / 2; i += 256) bin[i] = 0;
        __syncthreads();
        const long long P = (long long)(E >> 1);
        const long long pb = s * P / NSLD;
        const long long pe = (s + 1) * P / NSLD;
        const int4* ei4 = (const int4*)ei;
        for (long long g = pb + t; g < pe; g += 256) {
            int4 q = ei4[g];
            unsigned u0 = (unsigned)(q.y - base);
            unsigned u1 = (unsigned)(q.w - base);
            if (u0 < DRSZ) atomicAdd(&bin[u0 >> 1], 1u << ((u0 & 1) << 4));
            if (u1 < DRSZ) atomicAdd(&bin[u1 >> 1], 1u << ((u1 & 1) << 4));
        }
        if ((E & 1) && s == NSLD - 1 && t == 0) {
            unsigned u = (unsigned)(ei[2 * (E - 1) + 1] - base);
            if (u < DRSZ) atomicAdd(&bin[u >> 1], 1u << ((u & 1) << 4));
        }
        __syncthreads();
        const int lim = min(DRSZ, N - base);
        const int words = (lim + 1) >> 1;
        unsigned* dst = degrep + (size_t)s * N2 + (base >> 1);
        for (int i = t; i < words; i += 256) dst[i] = bin[i];
        return;
    }

    // ---- MFMA RNN: 4 independent waves, 16 nodes each, wave-private LDS ----
    const int w    = t >> 6;
    const int l    = t & 63;
    const int nl   = l & 15;
    const int quad = l >> 4;
    const int n0   = (blockIdx.x - RDN) * 64 + w * 16;

    unsigned short* hh = (unsigned short*)&smem[w * 512];          // 1024 u16
    unsigned short* hl = (unsigned short*)&smem[2048 + w * 512];   // 1024 u16
    float*          sx = (float*)&smem[4096 + w * 320];            // 320 f32

    // stage x (16 nodes x 20 steps, transposed [step][node])
    for (int i = l; i < 16 * TT; i += 64) {
        int nn = i / TT, tt = i - nn * TT;
        int n = n0 + nn; if (n >= N) n = N - 1;
        sx[tt * 16 + nn] = x[(size_t)n * TT + tt];
    }
    // zero h
    {
        uint4 zz = {0, 0, 0, 0};
        uint4* ph = (uint4*)hh;
        uint4* pl = (uint4*)hl;
#pragma unroll
        for (int i = 0; i < 2; ++i) { ph[l + 64 * i] = zz; pl[l + 64 * i] = zz; }
    }

    // W_hh -> hi/lo bf16 B-fragments (registers, trunc-split)
    short8 Bh[4][2], Bl[4][2];
#pragma unroll
    for (int tt2 = 0; tt2 < 4; ++tt2)
#pragma unroll
        for (int kc = 0; kc < 2; ++kc) {
            const float* wr = W_hh + (size_t)(16 * tt2 + nl) * HH + kc * 32 + quad * 8;
            float4 w0 = *(const float4*)(wr);
            float4 w1 = *(const float4*)(wr + 4);
            float wvv[8] = {w0.x, w0.y, w0.z, w0.w, w1.x, w1.y, w1.z, w1.w};
            short8 sh, sl;
#pragma unroll
            for (int j = 0; j < 8; ++j) {
                unsigned u  = fbits(wvv[j]);
                unsigned hb = u & 0xffff0000u;
                float lo = wvv[j] - bcast(hb);
                sh[j] = (short)(hb >> 16);
                sl[j] = (short)(fbits(lo) >> 16);
            }
            Bh[tt2][kc] = sh; Bl[tt2][kc] = sl;
        }

    // v = W_gcn^T w_fc
    float vl = 0.0f;
#pragma unroll 8
    for (int j = 0; j < HH; ++j) vl = fmaf(W_fc[j], W_gcn[j * HH + l], vl);

    float wih4[4], bs4[4], vv[4];
#pragma unroll
    for (int tt2 = 0; tt2 < 4; ++tt2) {
        int n = nl + 16 * tt2;
        wih4[tt2] = W_ih[n];
        bs4[tt2]  = b_ih[n] + b_hh[n];
        vv[tt2]   = __shfl(vl, n, 64);
    }

    const int ra = (l ^ ((l >> 4) & 1)) * 8;   // A-read offset (shorts)

    f32x4 C[4];

    for (int step = 0; step < TT; ++step) {
        const float4 xr = *(const float4*)&sx[step * 16 + quad * 4];
#pragma unroll
        for (int tt2 = 0; tt2 < 4; ++tt2) {
            C[tt2][0] = fmaf(xr.x, wih4[tt2], bs4[tt2]);
            C[tt2][1] = fmaf(xr.y, wih4[tt2], bs4[tt2]);
            C[tt2][2] = fmaf(xr.z, wih4[tt2], bs4[tt2]);
            C[tt2][3] = fmaf(xr.w, wih4[tt2], bs4[tt2]);
        }

#pragma unroll
        for (int kc = 0; kc < 2; ++kc) {
            short8 Ah = *(const short8*)&hh[kc * 512 + ra];
            short8 Al = *(const short8*)&hl[kc * 512 + ra];
#pragma unroll
            for (int tt2 = 0; tt2 < 4; ++tt2) {
                C[tt2] = __builtin_amdgcn_mfma_f32_16x16x32_bf16(Ah, Bh[tt2][kc], C[tt2], 0, 0, 0);
                C[tt2] = __builtin_amdgcn_mfma_f32_16x16x32_bf16(Ah, Bl[tt2][kc], C[tt2], 0, 0, 0);
                C[tt2] = __builtin_amdgcn_mfma_f32_16x16x32_bf16(Al, Bh[tt2][kc], C[tt2], 0, 0, 0);
            }
        }

        // tanh = 1 - 2*rcp(exp2(2.885*a)+1); trunc-split; per-lane ds_write_b16
#pragma unroll
        for (int tt2 = 0; tt2 < 4; ++tt2) {
            const int kc_d = tt2 >> 1;
            const int qa   = (nl >> 3) + 2 * (tt2 & 1);
            const int jj   = nl & 7;
#pragma unroll
            for (int r = 0; r < 4; ++r) {
                float eg = __builtin_amdgcn_exp2f(C[tt2][r] * 2.885390081777927f);
                float hv = fmaf(-2.0f, __builtin_amdgcn_rcpf(eg + 1.0f), 1.0f);
                C[tt2][r] = hv;
                unsigned um = fbits(hv);
                unsigned hb = um & 0xffff0000u;
                float lo = hv - bcast(hb);
                const int m   = quad * 4 + r;
                const int la  = m + 16 * qa;
                const int idx = kc_d * 512 + (la ^ ((la >> 4) & 1)) * 8 + jj;
                hh[idx] = (unsigned short)(um >> 16);
                hl[idx] = (unsigned short)(fbits(lo) >> 16);
            }
        }
    }

    // epilogue: z = h.v
#pragma unroll
    for (int r = 0; r < 4; ++r) {
        float p = 0.0f;
#pragma unroll
        for (int tt2 = 0; tt2 < 4; ++tt2) p = fmaf(C[tt2][r], vv[tt2], p);
        p += __shfl_xor(p, 1, 64);
        p += __shfl_xor(p, 2, 64);
        p += __shfl_xor(p, 4, 64);
        p += __shfl_xor(p, 8, 64);
        if (nl == 0) {
            const int n = n0 + quad * 4 + r;
            if (n < N) z[n] = p;
        }
    }
}

// reduce packed-u16 deg replicas; dinv = rsqrt(deg+1); w = dinv*z
__global__ __launch_bounds__(256) void k_w(const unsigned* __restrict__ degrep,
                                           const float* __restrict__ z,
                                           float* __restrict__ dinv,
                                           float* __restrict__ w, int N, int N2) {
    int n = blockIdx.x * blockDim.x + threadIdx.x;
    if (n >= N) return;
    const int wd = n >> 1, sh = (n & 1) << 4;
    unsigned d = 0;
#pragma unroll 8
    for (int s = 0; s < NSLD; ++s) d += (degrep[(size_t)s * N2 + wd] >> sh) & 0xffffu;
    float di = __frsqrt_rn((float)d + 1.0f);
    dinv[n] = di;
    w[n] = di * z[n];
}

// S aggregation via fp32 LDS bins; int4 = 2 edges per load. 224 blocks, one round.
__global__ __launch_bounds__(1024) void k_edge_bin(const int* __restrict__ ei,
                                                   const float* __restrict__ w,
                                                   float* __restrict__ Srep,
                                                   int N, int E, int R) {
    __shared__ float bin[RSZ];                    // 64 KB
    const int r = blockIdx.x % R;
    const int s = blockIdx.x / R;
    const int base = r * RSZ;
    for (int i = threadIdx.x; i < RSZ; i += 1024) bin[i] = 0.0f;
    __syncthreads();
    const long long P = (long long)(E >> 1);
    const long long pb = s * P / NSL;
    const long long pe = (s + 1) * P / NSL;
    const int4* ei4 = (const int4*)ei;
    for (long long g = pb + threadIdx.x; g < pe; g += 1024) {
        int4 q = ei4[g];
        unsigned u0 = (unsigned)(q.y - base);
        unsigned u1 = (unsigned)(q.w - base);
        if (u0 < RSZ) atomicAdd(&bin[u0], w[q.x]);
        if (u1 < RSZ) atomicAdd(&bin[u1], w[q.z]);
    }
    if ((E & 1) && s == NSL - 1 && threadIdx.x == 0) {
        unsigned u = (unsigned)(ei[2 * (E - 1) + 1] - base);
        if (u < RSZ) atomicAdd(&bin[u], w[ei[2 * (E - 1)]]);
    }
    __syncthreads();
    const int lim = min(RSZ, N - base);
    float* dst = Srep + (size_t)s * N + base;
    for (int i = threadIdx.x; i < lim; i += 1024) dst[i] = bin[i];
}

// out = dinv*(sum S_rep) + dinv*w + c,  c = w_fc.b_gcn + b_fc
__global__ __launch_bounds__(256) void k_final(const float* __restrict__ dinv,
                                               const float* __restrict__ Srep,
                                               const float* __restrict__ w,
                                               const float* __restrict__ b_gcn,
                                               const float* __restrict__ W_fc,
                                               const float* __restrict__ b_fc,
                                               float* __restrict__ out, int N)
{
    float c = b_fc[0];
#pragma unroll 8
    for (int j = 0; j < HH; ++j) c = fmaf(W_fc[j], b_gcn[j], c);
    int n = blockIdx.x * blockDim.x + threadIdx.x;
    if (n >= N) return;
    float S = 0.0f;
#pragma unroll 8
    for (int s = 0; s < NSL; ++s) S += Srep[(size_t)s * N + n];
    float d = dinv[n];
    out[n] = fmaf(d, S, fmaf(d, w[n], c));
}

extern "C" void kernel_launch(void* const* d_in, const int* in_sizes, int n_in,
                              void* d_out, int out_size, void* d_ws, size_t ws_size,
                              hipStream_t stream)
{
    const float* x     = (const float*)d_in[0];
    const int*   ei    = (const int*)d_in[1];
    const float* W_ih  = (const float*)d_in[2];
    const float* b_ih  = (const float*)d_in[3];
    const float* W_hh  = (const float*)d_in[4];
    const float* b_hh  = (const float*)d_in[5];
    const float* W_gcn = (const float*)d_in[6];
    const float* b_gcn = (const float*)d_in[7];
    const float* W_fc  = (const float*)d_in[8];
    const float* b_fc  = (const float*)d_in[9];
    float* out = (float*)d_out;

    const int N  = in_sizes[0] / TT;
    const int E  = in_sizes[1] / 2;
    const int N2 = (N + 1) / 2;
    const int RD = (N + DRSZ - 1) / DRSZ;      // deg ranges (u16 bins, 32 KB)
    const int RS = (N + RSZ - 1) / RSZ;        // S ranges (fp32 bins, 64 KB)

    char* ws = (char*)d_ws;
    size_t off = 0;
    auto alloc = [&](size_t bytes) { void* p = ws + off; off += (bytes + 255) & ~(size_t)255; return p; };
    unsigned* degrep = (unsigned*)alloc((size_t)NSLD * N2 * 4);  // packed u16 pairs
    float*    Srep   = (float*)   alloc((size_t)NSL * N * 4);
    float*    z      = (float*)   alloc((size_t)N * 4);
    float*    dinv   = (float*)   alloc((size_t)N * 4);
    float*    w      = (float*)   alloc((size_t)N * 4);
    // no memsets: every replica byte is overwritten by its (range, slice) owner

    const int rnnBlocks = (N + 63) / 64;
    k_fused   <<<RD * NSLD + rnnBlocks, 256, 0, stream>>>(x, W_ih, b_ih, W_hh, b_hh,
                                                          W_gcn, W_fc, ei, degrep,
                                                          z, N, E, RD, N2);
    k_w       <<<(N + 255) / 256, 256, 0, stream>>>(degrep, z, dinv, w, N, N2);
    k_edge_bin<<<RS * NSL, 1024, 0, stream>>>(ei, w, Srep, N, E, RS);
    k_final   <<<(N + 255) / 256, 256, 0, stream>>>(dinv, Srep, w, b_gcn, W_fc, b_fc, out, N);
}

// Round 20
// 230.898 us; speedup vs baseline: 1.1709x; 1.0386x over previous
//
#include <hip/hip_runtime.h>

#define TT 20
#define HH 64
#define RSZ 16384      // fp32 S-bin range (64 KB LDS)
#define DRSZ 16384     // u16 deg-bin range (32 KB LDS, shared with RNN path)
#define NSL 64         // edge slices for S pass
#define NSLD 32        // edge slices for fused deg pass

typedef __attribute__((ext_vector_type(8))) short short8;   // 8 bf16 (MFMA A/B frag)
typedef __attribute__((ext_vector_type(4))) float f32x4;    // MFMA C/D frag

__device__ __forceinline__ unsigned fbits(float f) { union { float f; unsigned u; } v; v.f = f; return v.u; }
__device__ __forceinline__ float bcast(unsigned u) { union { float f; unsigned u; } v; v.u = u; return v.f; }

// Fused: blocks [0, RD*NSLD) = deg histogram via LDS u16 bins (VMEM/L3 pipes);
// blocks >= RD*NSLD = pure MFMA RNN (VALU/LDS/MFMA pipes). One 32 KB smem pool.
__global__ __launch_bounds__(256, 4) void k_fused(
    const float* __restrict__ x,
    const float* __restrict__ W_ih, const float* __restrict__ b_ih,
    const float* __restrict__ W_hh, const float* __restrict__ b_hh,
    const float* __restrict__ W_gcn, const float* __restrict__ W_fc,
    const int* __restrict__ ei, unsigned* __restrict__ degrep,
    float* __restrict__ z, int N, int E, int RD, int N2)
{
    __shared__ __align__(16) unsigned smem[8192];   // 32 KB

    const int t = threadIdx.x;
    const int RDN = RD * NSLD;

    if (blockIdx.x < RDN) {
        // ---- deg histogram: packed-u16 LDS bins, int4 = 2 edges per load ----
        unsigned* bin = smem;                       // 8192 words = 16384 u16 bins
        const int r = blockIdx.x % RD;
        const int s = blockIdx.x / RD;
        const int base = r * DRSZ;
        for (int i = t; i < DRSZ / 2; i += 256) bin[i] = 0;
        __syncthreads();
        const long long P = (long long)(E >> 1);
        const long long pb = s * P / NSLD;
        const long long pe = (s + 1) * P / NSLD;
        const int4* ei4 = (const int4*)ei;
        for (long long g = pb + t; g < pe; g += 256) {
            int4 q = ei4[g];
            unsigned u0 = (unsigned)(q.y - base);
            unsigned u1 = (unsigned)(q.w - base);
            if (u0 < DRSZ) atomicAdd(&bin[u0 >> 1], 1u << ((u0 & 1) << 4));
            if (u1 < DRSZ) atomicAdd(&bin[u1 >> 1], 1u << ((u1 & 1) << 4));
        }
        if ((E & 1) && s == NSLD - 1 && t == 0) {
            unsigned u = (unsigned)(ei[2 * (E - 1) + 1] - base);
            if (u < DRSZ) atomicAdd(&bin[u >> 1], 1u << ((u & 1) << 4));
        }
        __syncthreads();
        const int lim = min(DRSZ, N - base);
        const int words = (lim + 1) >> 1;
        unsigned* dst = degrep + (size_t)s * N2 + (base >> 1);
        for (int i = t; i < words; i += 256) dst[i] = bin[i];
        return;
    }

    // ---- MFMA RNN: 4 independent waves, 16 nodes each, wave-private LDS ----
    const int w    = t >> 6;
    const int l    = t & 63;
    const int nl   = l & 15;
    const int quad = l >> 4;
    const int n0   = (blockIdx.x - RDN) * 64 + w * 16;

    unsigned short* hh = (unsigned short*)&smem[w * 512];          // 1024 u16
    unsigned short* hl = (unsigned short*)&smem[2048 + w * 512];   // 1024 u16
    float*          sx = (float*)&smem[4096 + w * 320];            // 320 f32

    // stage x (16 nodes x 20 steps, transposed [step][node])
    for (int i = l; i < 16 * TT; i += 64) {
        int nn = i / TT, tt = i - nn * TT;
        int n = n0 + nn; if (n >= N) n = N - 1;
        sx[tt * 16 + nn] = x[(size_t)n * TT + tt];
    }
    // zero h
    {
        uint4 zz = {0, 0, 0, 0};
        uint4* ph = (uint4*)hh;
        uint4* pl = (uint4*)hl;
#pragma unroll
        for (int i = 0; i < 2; ++i) { ph[l + 64 * i] = zz; pl[l + 64 * i] = zz; }
    }

    // W_hh -> hi/lo bf16 B-fragments (registers, trunc-split)
    short8 Bh[4][2], Bl[4][2];
#pragma unroll
    for (int tt2 = 0; tt2 < 4; ++tt2)
#pragma unroll
        for (int kc = 0; kc < 2; ++kc) {
            const float* wr = W_hh + (size_t)(16 * tt2 + nl) * HH + kc * 32 + quad * 8;
            float4 w0 = *(const float4*)(wr);
            float4 w1 = *(const float4*)(wr + 4);
            float wvv[8] = {w0.x, w0.y, w0.z, w0.w, w1.x, w1.y, w1.z, w1.w};
            short8 sh, sl;
#pragma unroll
            for (int j = 0; j < 8; ++j) {
                unsigned u  = fbits(wvv[j]);
                unsigned hb = u & 0xffff0000u;
                float lo = wvv[j] - bcast(hb);
                sh[j] = (short)(hb >> 16);
                sl[j] = (short)(fbits(lo) >> 16);
            }
            Bh[tt2][kc] = sh; Bl[tt2][kc] = sl;
        }

    // v = W_gcn^T w_fc
    float vl = 0.0f;
#pragma unroll 8
    for (int j = 0; j < HH; ++j) vl = fmaf(W_fc[j], W_gcn[j * HH + l], vl);

    float wih4[4], bs4[4], vv[4];
#pragma unroll
    for (int tt2 = 0; tt2 < 4; ++tt2) {
        int n = nl + 16 * tt2;
        wih4[tt2] = W_ih[n];
        bs4[tt2]  = b_ih[n] + b_hh[n];
        vv[tt2]   = __shfl(vl, n, 64);
    }

    const int ra = (l ^ ((l >> 4) & 1)) * 8;   // A-read offset (shorts)

    f32x4 C[4];

    for (int step = 0; step < TT; ++step) {
        const float4 xr = *(const float4*)&sx[step * 16 + quad * 4];
#pragma unroll
        for (int tt2 = 0; tt2 < 4; ++tt2) {
            C[tt2][0] = fmaf(xr.x, wih4[tt2], bs4[tt2]);
            C[tt2][1] = fmaf(xr.y, wih4[tt2], bs4[tt2]);
            C[tt2][2] = fmaf(xr.z, wih4[tt2], bs4[tt2]);
            C[tt2][3] = fmaf(xr.w, wih4[tt2], bs4[tt2]);
        }

#pragma unroll
        for (int kc = 0; kc < 2; ++kc) {
            short8 Ah = *(const short8*)&hh[kc * 512 + ra];
            short8 Al = *(const short8*)&hl[kc * 512 + ra];
#pragma unroll
            for (int tt2 = 0; tt2 < 4; ++tt2) {
                C[tt2] = __builtin_amdgcn_mfma_f32_16x16x32_bf16(Ah, Bh[tt2][kc], C[tt2], 0, 0, 0);
                C[tt2] = __builtin_amdgcn_mfma_f32_16x16x32_bf16(Ah, Bl[tt2][kc], C[tt2], 0, 0, 0);
                C[tt2] = __builtin_amdgcn_mfma_f32_16x16x32_bf16(Al, Bh[tt2][kc], C[tt2], 0, 0, 0);
            }
        }

        // tanh = 1 - 2*rcp(exp2(2.885*a)+1); trunc-split; per-lane ds_write_b16
#pragma unroll
        for (int tt2 = 0; tt2 < 4; ++tt2) {
            const int kc_d = tt2 >> 1;
            const int qa   = (nl >> 3) + 2 * (tt2 & 1);
            const int jj   = nl & 7;
#pragma unroll
            for (int r = 0; r < 4; ++r) {
                float eg = __builtin_amdgcn_exp2f(C[tt2][r] * 2.885390081777927f);
                float hv = fmaf(-2.0f, __builtin_amdgcn_rcpf(eg + 1.0f), 1.0f);
                C[tt2][r] = hv;
                unsigned um = fbits(hv);
                unsigned hb = um & 0xffff0000u;
                float lo = hv - bcast(hb);
                const int m   = quad * 4 + r;
                const int la  = m + 16 * qa;
                const int idx = kc_d * 512 + (la ^ ((la >> 4) & 1)) * 8 + jj;
                hh[idx] = (unsigned short)(um >> 16);
                hl[idx] = (unsigned short)(fbits(lo) >> 16);
            }
        }
    }

    // epilogue: z = h.v
#pragma unroll
    for (int r = 0; r < 4; ++r) {
        float p = 0.0f;
#pragma unroll
        for (int tt2 = 0; tt2 < 4; ++tt2) p = fmaf(C[tt2][r], vv[tt2], p);
        p += __shfl_xor(p, 1, 64);
        p += __shfl_xor(p, 2, 64);
        p += __shfl_xor(p, 4, 64);
        p += __shfl_xor(p, 8, 64);
        if (nl == 0) {
            const int n = n0 + quad * 4 + r;
            if (n < N) z[n] = p;
        }
    }
}

// reduce packed-u16 deg replicas; dinv = rsqrt(deg+1); w = dinv*z
__global__ __launch_bounds__(256) void k_w(const unsigned* __restrict__ degrep,
                                           const float* __restrict__ z,
                                           float* __restrict__ dinv,
                                           float* __restrict__ w, int N, int N2) {
    int n = blockIdx.x * blockDim.x + threadIdx.x;
    if (n >= N) return;
    const int wd = n >> 1, sh = (n & 1) << 4;
    unsigned d = 0;
#pragma unroll 8
    for (int s = 0; s < NSLD; ++s) d += (degrep[(size_t)s * N2 + wd] >> sh) & 0xffffu;
    float di = __frsqrt_rn((float)d + 1.0f);
    dinv[n] = di;
    w[n] = di * z[n];
}

// S aggregation via fp32 LDS bins; int4 = 2 edges per load.
__global__ __launch_bounds__(1024) void k_edge_bin(const int* __restrict__ ei,
                                                   const float* __restrict__ w,
                                                   float* __restrict__ Srep,
                                                   int N, int E, int R) {
    __shared__ float bin[RSZ];                    // 64 KB
    const int r = blockIdx.x % R;
    const int s = blockIdx.x / R;
    const int base = r * RSZ;
    for (int i = threadIdx.x; i < RSZ; i += 1024) bin[i] = 0.0f;
    __syncthreads();
    const long long P = (long long)(E >> 1);
    const long long pb = s * P / NSL;
    const long long pe = (s + 1) * P / NSL;
    const int4* ei4 = (const int4*)ei;
    for (long long g = pb + threadIdx.x; g < pe; g += 1024) {
        int4 q = ei4[g];
        unsigned u0 = (unsigned)(q.y - base);
        unsigned u1 = (unsigned)(q.w - base);
        if (u0 < RSZ) atomicAdd(&bin[u0], w[q.x]);
        if (u1 < RSZ) atomicAdd(&bin[u1], w[q.z]);
    }
    if ((E & 1) && s == NSL - 1 && threadIdx.x == 0) {
        unsigned u = (unsigned)(ei[2 * (E - 1) + 1] - base);
        if (u < RSZ) atomicAdd(&bin[u], w[ei[2 * (E - 1)]]);
    }
    __syncthreads();
    const int lim = min(RSZ, N - base);
    float* dst = Srep + (size_t)s * N + base;
    for (int i = threadIdx.x; i < lim; i += 1024) dst[i] = bin[i];
}

// out = dinv*(sum S_rep) + dinv*w + c,  c = w_fc.b_gcn + b_fc
__global__ __launch_bounds__(256) void k_final(const float* __restrict__ dinv,
                                               const float* __restrict__ Srep,
                                               const float* __restrict__ w,
                                               const float* __restrict__ b_gcn,
                                               const float* __restrict__ W_fc,
                                               const float* __restrict__ b_fc,
                                               float* __restrict__ out, int N)
{
    float c = b_fc[0];
#pragma unroll 8
    for (int j = 0; j < HH; ++j) c = fmaf(W_fc[j], b_gcn[j], c);
    int n = blockIdx.x * blockDim.x + threadIdx.x;
    if (n >= N) return;
    float S = 0.0f;
#pragma unroll 8
    for (int s = 0; s < NSL; ++s) S += Srep[(size_t)s * N + n];
    float d = dinv[n];
    out[n] = fmaf(d, S, fmaf(d, w[n], c));
}

extern "C" void kernel_launch(void* const* d_in, const int* in_sizes, int n_in,
                              void* d_out, int out_size, void* d_ws, size_t ws_size,
                              hipStream_t stream)
{
    const float* x     = (const float*)d_in[0];
    const int*   ei    = (const int*)d_in[1];
    const float* W_ih  = (const float*)d_in[2];
    const float* b_ih  = (const float*)d_in[3];
    const float* W_hh  = (const float*)d_in[4];
    const float* b_hh  = (const float*)d_in[5];
    const float* W_gcn = (const float*)d_in[6];
    const float* b_gcn = (const float*)d_in[7];
    const float* W_fc  = (const float*)d_in[8];
    const float* b_fc  = (const float*)d_in[9];
    float* out = (float*)d_out;

    const int N  = in_sizes[0] / TT;
    const int E  = in_sizes[1] / 2;
    const int N2 = (N + 1) / 2;
    const int RD = (N + DRSZ - 1) / DRSZ;      // deg ranges (u16 bins, 32 KB)
    const int RS = (N + RSZ - 1) / RSZ;        // S ranges (fp32 bins, 64 KB)

    char* ws = (char*)d_ws;
    size_t off = 0;
    auto alloc = [&](size_t bytes) { void* p = ws + off; off += (bytes + 255) & ~(size_t)255; return p; };
    unsigned* degrep = (unsigned*)alloc((size_t)NSLD * N2 * 4);  // packed u16 pairs
    float*    Srep   = (float*)   alloc((size_t)NSL * N * 4);
    float*    z      = (float*)   alloc((size_t)N * 4);
    float*    dinv   = (float*)   alloc((size_t)N * 4);
    float*    w      = (float*)   alloc((size_t)N * 4);
    // no memsets: every replica byte is overwritten by its (range, slice) owner

    const int rnnBlocks = (N + 63) / 64;
    k_fused   <<<RD * NSLD + rnnBlocks, 256, 0, stream>>>(x, W_ih, b_ih, W_hh, b_hh,
                                                          W_gcn, W_fc, ei, degrep,
                                                          z, N, E, RD, N2);
    k_w       <<<(N + 255) / 256, 256, 0, stream>>>(degrep, z, dinv, w, N, N2);
    k_edge_bin<<<RS * NSL, 1024, 0, stream>>>(ei, w, Srep, N, E, RS);
    k_final   <<<(N + 255) / 256, 256, 0, stream>>>(dinv, Srep, w, b_gcn, W_fc, b_fc, out, N);
}